// Round 9
// baseline (209.680 us; speedup 1.0000x reference)
//
#include <hip/hip_runtime.h>
#include <hip/hip_fp16.h>

#define N_PTS 100000
#define MU_F  100.0f

typedef unsigned int uint;
typedef _Float16 h2 __attribute__((ext_vector_type(2)));
typedef float f2 __attribute__((ext_vector_type(2)));

#define E_SCALE 16384.0f
#define E_SCALE_INV (1.0f / 16384.0f)

static __device__ inline h2 h2pack(float a, float b) {
    return __builtin_bit_cast(h2, __builtin_amdgcn_cvt_pkrtz(a, b));
}
static __device__ inline float fdot2f(h2 a, h2 b, float c) {
    return __builtin_amdgcn_fdot2(a, b, c, false);
}
static __device__ inline h2 h2fma(h2 a, h2 b, h2 c) {
#if __has_builtin(__builtin_elementwise_fma)
    return __builtin_elementwise_fma(a, b, c);
#else
    return a * b + c;
#endif
}
static __device__ inline h2 h2max(h2 a, h2 b) {
#if __has_builtin(__builtin_elementwise_max)
    return __builtin_elementwise_max(a, b);
#else
    h2 r;
    r.x = a.x > b.x ? a.x : b.x;
    r.y = a.y > b.y ? a.y : b.y;
    return r;
#endif
}

#define ENC_BLKS 256
#define TR_BLKS  1563            // ceil(100000/64), fused into K1 (leaf work)
#define S_BLKS   2048            // grid >= 8 blocks/CU so (256,8) can bite
#define S_PCH    49              // ceil(100000/2048)
#define NPAIRS   (N_PTS / 2)     // 50000
#define M_BLKS   2048
#define M_CH     ((NPAIRS + M_BLKS - 1) / M_BLKS)   // 25

// ws layout (memset zeroes [0,4224): enc + S):
//   [0,128)        enc (32 f, atomicAdd target)
//   [128,4224)     S (1024 f, atomicAdd target)
//   [4224,6272)    invFG (512 f)
//   [6272,7296)    invHLG (256 h2)
//   [532480,...)   decT (N*32 fp16, 6.4 MB)
// NO cross-block fences (round-7: __threadfence on non-coherent per-XCD L2
// = writeback storm). Cross-kernel visibility rides dispatch boundaries;
// in-kernel accumulation is device-scope atomicAdd (fence-free).

// ---------------------------------------------------------------------------
// K1: encode (256 blocks) || dec transpose (1563 blocks) — both are
// dependency-free leaves; fusing them takes the transpose off the critical
// path between k_tab and k_S (round-8 post-mortem).
// ---------------------------------------------------------------------------
__global__ __launch_bounds__(256) void k_prep_tr(const float* __restrict__ x,
                                                 const float* __restrict__ encW,
                                                 const float* __restrict__ encB,
                                                 float* __restrict__ enc,
                                                 const float* __restrict__ dec,
                                                 __half* __restrict__ decT) {
    int b = blockIdx.x;
    if (b < ENC_BLKS) {
        // ----- encode: enc[row] = x . encW[row,:] + encB[row]
        int row = b & 31;
        int chunk = b >> 5;              // 0..7
        const int CH = N_PTS / 8;        // 12500
        int base = chunk * CH;
        const float4* W4 = reinterpret_cast<const float4*>(encW + (size_t)row * N_PTS + base);
        const float4* x4 = reinterpret_cast<const float4*>(x + base);
        const int nv = CH / 4;           // 3125
        float acc = 0.f;
        for (int idx = threadIdx.x; idx < nv; idx += 256) {
            float4 w = W4[idx];
            float4 xv = x4[idx];
            acc += w.x * xv.x + w.y * xv.y + w.z * xv.z + w.w * xv.w;
        }
        #pragma unroll
        for (int off = 32; off > 0; off >>= 1) acc += __shfl_down(acc, off);
        __shared__ float sred[4];
        int wid = threadIdx.x >> 6;
        if ((threadIdx.x & 63) == 0) sred[wid] = acc;
        __syncthreads();
        if (threadIdx.x == 0) {
            float s = sred[0] + sred[1] + sred[2] + sred[3];
            if (chunk == 0) s += encB[row];
            atomicAdd(enc + row, s);
        }
    } else {
        // ----- transpose dec [32,N] f32 -> decT [N,32] fp16 (64B rows)
        __shared__ float tile[32][65];
        int j0 = (b - ENC_BLKS) * 64;
        int col = threadIdx.x & 63;
        int r0 = threadIdx.x >> 6;       // 0..3
        #pragma unroll
        for (int it = 0; it < 8; ++it) {
            int row = it * 4 + r0;
            int j = j0 + col;
            float v = (j < N_PTS) ? dec[(size_t)row * N_PTS + j] : 0.f;
            tile[row][col] = v;
        }
        __syncthreads();
        #pragma unroll
        for (int it = 0; it < 4; ++it) {
            int idx = it * 256 + threadIdx.x;
            int j = idx >> 4;            // 0..63
            int p = idx & 15;            // i-pair
            int jj = j0 + j;
            if (jj < N_PTS) {
                __half2 h = __halves2half2(__float2half(tile[2 * p][j]),
                                           __float2half(tile[2 * p + 1][j]));
                *reinterpret_cast<__half2*>(decT + (size_t)jj * 32 + 2 * p) = h;
            }
        }
    }
}

// ---------------------------------------------------------------------------
// K_tab (1 block): build invFG[512] (f32) and invHLG[256] (packed h2) ONCE.
// invF[c*32+i] = 1/(sigmoid(enc.bw_w[i*16+c]+b)*MU/60)^2
// ---------------------------------------------------------------------------
__global__ __launch_bounds__(256) void k_tab(const float* __restrict__ enc_g,
                                             const float* __restrict__ bw_w,
                                             const float* __restrict__ bw_b,
                                             float* __restrict__ invFG,
                                             h2* __restrict__ invHLG) {
    __shared__ float encL[32];
    __shared__ float invF[512];
    if (threadIdx.x < 32) encL[threadIdx.x] = enc_g[threadIdx.x];
    __syncthreads();
    for (int r = threadIdx.x; r < 512; r += 256) {
        int i = r >> 4, c = r & 15;
        const float4* wr4 = reinterpret_cast<const float4*>(bw_w + (size_t)r * 32);
        float z = bw_b[r];
        #pragma unroll
        for (int p4 = 0; p4 < 8; ++p4) {
            float4 wv = wr4[p4];
            z = fmaf(encL[4 * p4 + 0], wv.x, z);
            z = fmaf(encL[4 * p4 + 1], wv.y, z);
            z = fmaf(encL[4 * p4 + 2], wv.z, z);
            z = fmaf(encL[4 * p4 + 3], wv.w, z);
        }
        float s = 1.f / (1.f + __expf(-z));
        float wmu = s * (MU_F / 60.0f);
        float iv = 1.f / (wmu * wmu);
        invF[c * 32 + i] = iv;
        invFG[c * 32 + i] = iv;
    }
    __syncthreads();
    {
        int t = threadIdx.x;             // 16c x 4q x 4tt
        int c = t >> 4, q = (t >> 2) & 3, tt = t & 3;
        int i0 = q * 8 + 2 * tt;
        invHLG[t] = h2pack(fminf(invF[c * 32 + i0], 6.0e4f),
                           fminf(invF[c * 32 + i0 + 1], 6.0e4f));
    }
}

// ---------------------------------------------------------------------------
// K2: pure S pass (transpose moved to K1). 2048 blocks x 49 points,
// cell-ownership (thread owns 4 S cells), fence-free atomicAdd epilogue.
// (256,8): measured live set ~20-30 VGPR, cap 64, no spill; grid 2048 =
// exactly 8 blocks/CU so the bound actually doubles resident waves.
// ---------------------------------------------------------------------------
__global__ __launch_bounds__(256, 8) void k_S(const float* __restrict__ invFG,
                                              const float* __restrict__ nd,
                                              const int* __restrict__ labels,
                                              float* __restrict__ S) {
    __shared__ float invF[512];
    if (threadIdx.x < 128)               // 2KB coalesced table load
        reinterpret_cast<float4*>(invF)[threadIdx.x] =
            reinterpret_cast<const float4*>(invFG)[threadIdx.x];
    __syncthreads();

    int kk = threadIdx.x & 31;
    int ig = threadIdx.x >> 5;           // 0..7
    int start = blockIdx.x * S_PCH;
    int jend = min(start + S_PCH, N_PTS);

    float a0 = 0.f, a1 = 0.f, a2 = 0.f, a3 = 0.f;

    // padded points get d=1e15 -> relu(1 - 1e30*inv) == 0 exactly (inv>=0.36).
    auto ld4 = [&](int jbase, float* d, int* cc) {
        #pragma unroll
        for (int u = 0; u < 4; ++u) {
            int j = jbase + u;
            int jc = min(j, N_PTS - 1);
            float dv = __builtin_nontemporal_load(&nd[(size_t)jc * 32 + kk]);
            cc[u] = labels[jc];          // uniform j -> scalar load
            d[u] = (j < jend) ? dv : 1.0e15f;
        }
    };
    float dA[4], dB[4], dC[4]; int cA[4], cB[4], cC[4];
    ld4(start, dA, cA);
    ld4(start + 4, dB, cB);
    for (int jj = start; jj < jend; jj += 4) {
        ld4(jj + 8, dC, cC);             // 3-deep: A compute, B ready, C inflight
        #pragma unroll
        for (int u = 0; u < 4; ++u) {
            float4 iv = *reinterpret_cast<const float4*>(&invF[cA[u] * 32 + ig * 4]);
            float d2 = dA[u] * dA[u];
            a0 += fmaxf(fmaf(d2, -iv.x, 1.f), 0.f);
            a1 += fmaxf(fmaf(d2, -iv.y, 1.f), 0.f);
            a2 += fmaxf(fmaf(d2, -iv.z, 1.f), 0.f);
            a3 += fmaxf(fmaf(d2, -iv.w, 1.f), 0.f);
        }
        #pragma unroll
        for (int u = 0; u < 4; ++u) {
            dA[u] = dB[u]; cA[u] = cB[u];
            dB[u] = dC[u]; cB[u] = cC[u];
        }
    }

    int cell = (ig * 4) * 32 + kk;       // i = ig*4+r -> cell + r*32
    atomicAdd(&S[cell], a0);             // device-scope, fence-free
    atomicAdd(&S[cell + 32], a1);
    atomicAdd(&S[cell + 64], a2);
    atomicAdd(&S[cell + 96], a3);
}

// ---------------------------------------------------------------------------
// K4 (main): decT gather loop. Round-8: (256,6) -> 44% occupancy, VALUBusy
// 28%, latency-bound; pipeline keeps collapsing (VGPR=36) so buy TLP not
// ILP: (256,8) = 32 waves/CU, grid 2048 = one exact residency round.
// Per-thread Eh build from enc+S (identical f32 math as old k_elf).
// ---------------------------------------------------------------------------
__global__ __launch_bounds__(256, 8) void k_main(const h2* __restrict__ invHLG,
                                                 const float* __restrict__ enc_g,
                                                 const float* __restrict__ S_g,
                                                 const float* __restrict__ nd,
                                                 const int* __restrict__ nid,
                                                 const int* __restrict__ labels,
                                                 const __half* __restrict__ decT,
                                                 float* __restrict__ out) {
    __shared__ h2 invHL[256];            // [c][q][t] : c*16 + q*4 + t
    if (threadIdx.x < 64)                // 1KB coalesced copy
        reinterpret_cast<uint4*>(invHL)[threadIdx.x] =
            reinterpret_cast<const uint4*>(invHLG)[threadIdx.x];
    __syncthreads();

    int lane = threadIdx.x & 63;
    int R = lane >> 2;                   // 0..15
    int q = lane & 3;                    // i-quarter / row quad

    // per-thread E tables: ELf[t] = enc[t>>5]/S[t]*E_SCALE; (i0*32+R)>>5 == i0.
    h2 EhA[4], EhB[4];
    #pragma unroll
    for (int t = 0; t < 4; ++t) {
        int i0 = q * 8 + 2 * t;
        float e0 = enc_g[i0], e1 = enc_g[i0 + 1];
        float sA0 = S_g[i0 * 32 + R],      sA1 = S_g[(i0 + 1) * 32 + R];
        float sB0 = S_g[i0 * 32 + R + 16], sB1 = S_g[(i0 + 1) * 32 + R + 16];
        EhA[t] = h2pack(e0 / sA0 * E_SCALE, e1 / sA1 * E_SCALE);
        EhB[t] = h2pack(e0 / sB0 * E_SCALE, e1 / sB1 * E_SCALE);
    }
    const h2 zero2 = h2pack(0.f, 0.f);
    const h2 one2 = h2pack(1.f, 1.f);

    int w = threadIdx.x >> 6;            // wave 0..3
    int start = blockIdx.x * M_CH;
    int pend = min(start + M_CH, NPAIRS);
    int pa = start + w;
    const uint4* decQ = reinterpret_cast<const uint4*>(decT);
    if (pa >= pend) return;

    auto load_ldd = [&](int pc, int* id, float* dd, int& c0, int& c1) {
        pc = min(pc, NPAIRS - 1);
        int j0 = 2 * pc, j1 = j0 + 1;
        #pragma unroll
        for (int s = 0; s < 4; ++s) {
            size_t idx = (size_t)((s >> 1) ? j1 : j0) * 32 + (s & 1) * 16 + R;
            id[s] = __builtin_nontemporal_load(&nid[idx]);
            dd[s] = __builtin_nontemporal_load(&nd[idx]);
        }
        c0 = labels[j0];
        c1 = labels[j1];
    };
    auto load_rows = [&](const int* id, uint4* r) {
        #pragma unroll
        for (int s = 0; s < 4; ++s)
            r[s] = decQ[(size_t)id[s] * 4 + q];
    };
    auto load_ih = [&](int c0, int c1, h2* ih0, h2* ih1) {
        uint4 a = *reinterpret_cast<const uint4*>(&invHL[c0 * 16 + q * 4]);
        uint4 bq = *reinterpret_cast<const uint4*>(&invHL[c1 * 16 + q * 4]);
        ih0[0] = __builtin_bit_cast(h2, a.x);  ih0[1] = __builtin_bit_cast(h2, a.y);
        ih0[2] = __builtin_bit_cast(h2, a.z);  ih0[3] = __builtin_bit_cast(h2, a.w);
        ih1[0] = __builtin_bit_cast(h2, bq.x); ih1[1] = __builtin_bit_cast(h2, bq.y);
        ih1[2] = __builtin_bit_cast(h2, bq.z); ih1[3] = __builtin_bit_cast(h2, bq.w);
    };

    int ida[4], idb[4]; float dda[4], ddb[4];
    int ca0, ca1, cb0, cb1;
    uint4 ra[4], rb[4];
    h2 ihA0[4], ihA1[4];

    load_ldd(pa, ida, dda, ca0, ca1);
    load_ldd(pa + 4, idb, ddb, cb0, cb1);
    load_rows(ida, ra);
    load_ih(ca0, ca1, ihA0, ihA1);

    while (pa < pend) {
        load_rows(idb, rb);
        h2 ihB0[4], ihB1[4];
        load_ih(cb0, cb1, ihB0, ihB1);
        int idc[4]; float ddc[4]; int cc0, cc1;
        load_ldd(pa + 8, idc, ddc, cc0, cc1);

        float d20 = dda[0] * dda[0];
        float d21 = dda[1] * dda[1];
        float d22 = dda[2] * dda[2];
        float d23 = dda[3] * dda[3];
        h2 md0 = h2pack(-d20, -d20);
        h2 md1 = h2pack(-d21, -d21);
        h2 md2 = h2pack(-d22, -d22);
        h2 md3 = h2pack(-d23, -d23);

        float a0 = 0.f, a1 = 0.f, a2 = 0.f, a3 = 0.f;
        #pragma unroll
        for (int t = 0; t < 4; ++t) {
            uint dw0 = (t == 0) ? ra[0].x : (t == 1) ? ra[0].y : (t == 2) ? ra[0].z : ra[0].w;
            uint dw1 = (t == 0) ? ra[1].x : (t == 1) ? ra[1].y : (t == 2) ? ra[1].z : ra[1].w;
            uint dw2 = (t == 0) ? ra[2].x : (t == 1) ? ra[2].y : (t == 2) ? ra[2].z : ra[2].w;
            uint dw3 = (t == 0) ? ra[3].x : (t == 1) ? ra[3].y : (t == 2) ? ra[3].z : ra[3].w;
            {
                h2 wv = h2max(h2fma(md0, ihA0[t], one2), zero2);
                a0 = fdot2f(wv * EhA[t], __builtin_bit_cast(h2, dw0), a0);
            }
            {
                h2 wv = h2max(h2fma(md1, ihA0[t], one2), zero2);
                a1 = fdot2f(wv * EhB[t], __builtin_bit_cast(h2, dw1), a1);
            }
            {
                h2 wv = h2max(h2fma(md2, ihA1[t], one2), zero2);
                a2 = fdot2f(wv * EhA[t], __builtin_bit_cast(h2, dw2), a2);
            }
            {
                h2 wv = h2max(h2fma(md3, ihA1[t], one2), zero2);
                a3 = fdot2f(wv * EhB[t], __builtin_bit_cast(h2, dw3), a3);
            }
        }
        float u = a0 + a1;               // j0 partial
        float v = a2 + a3;               // j1 partial
        #pragma unroll
        for (int off = 32; off > 0; off >>= 1) {
            u += __shfl_xor(u, off);
            v += __shfl_xor(v, off);
        }
        if (lane == 0)  out[2 * pa]     = u * E_SCALE_INV;
        if (lane == 32) out[2 * pa + 1] = v * E_SCALE_INV;

        ca0 = cb0; ca1 = cb1; cb0 = cc0; cb1 = cc1;
        #pragma unroll
        for (int s = 0; s < 4; ++s) {
            dda[s] = ddb[s]; ddb[s] = ddc[s];
            ida[s] = idb[s]; idb[s] = idc[s];
            ra[s] = rb[s];
            ihA0[s] = ihB0[s]; ihA1[s] = ihB1[s];
        }
        pa += 4;
    }
}

// ---------------------------------------------------------------------------
extern "C" void kernel_launch(void* const* d_in, const int* in_sizes, int n_in,
                              void* d_out, int out_size, void* d_ws, size_t ws_size,
                              hipStream_t stream) {
    const float* x     = (const float*)d_in[0];
    const float* enc_w = (const float*)d_in[1];
    const float* enc_b = (const float*)d_in[2];
    const float* dec   = (const float*)d_in[3];
    const float* bw_w  = (const float*)d_in[4];
    const float* bw_b  = (const float*)d_in[5];
    const float* nd    = (const float*)d_in[6];
    const int*   nid   = (const int*)d_in[7];
    const int*   labels= (const int*)d_in[8];
    float* out = (float*)d_out;

    char* ws = (char*)d_ws;
    float* enc    = (float*)(ws + 0);
    float* S      = (float*)(ws + 128);
    float* invFG  = (float*)(ws + 4224);
    h2*    invHLG = (h2*)(ws + 6272);
    __half* decT  = (__half*)(ws + 532480);

    (void)hipMemsetAsync(d_ws, 0, 4224, stream);    // enc + S
    k_prep_tr<<<dim3(ENC_BLKS + TR_BLKS), dim3(256), 0, stream>>>(
        x, enc_w, enc_b, enc, dec, decT);
    k_tab<<<dim3(1), dim3(256), 0, stream>>>(enc, bw_w, bw_b, invFG, invHLG);
    k_S<<<dim3(S_BLKS), dim3(256), 0, stream>>>(invFG, nd, labels, S);
    k_main<<<dim3(M_BLKS), dim3(256), 0, stream>>>(invHLG, enc, S, nd, nid,
                                                   labels, decT, out);
}

// Round 11
// 173.319 us; speedup vs baseline: 1.2098x; 1.2098x over previous
//
#include <hip/hip_runtime.h>
#include <hip/hip_fp16.h>

#define N_PTS 100000
#define MU_F  100.0f

typedef unsigned int uint;
typedef _Float16 h2 __attribute__((ext_vector_type(2)));
typedef float f2 __attribute__((ext_vector_type(2)));

#define E_SCALE 16384.0f
#define E_SCALE_INV (1.0f / 16384.0f)

static __device__ inline h2 h2pack(float a, float b) {
    return __builtin_bit_cast(h2, __builtin_amdgcn_cvt_pkrtz(a, b));
}
static __device__ inline float fdot2f(h2 a, h2 b, float c) {
    return __builtin_amdgcn_fdot2(a, b, c, false);
}
static __device__ inline h2 h2fma(h2 a, h2 b, h2 c) {
#if __has_builtin(__builtin_elementwise_fma)
    return __builtin_elementwise_fma(a, b, c);
#else
    return a * b + c;
#endif
}
static __device__ inline h2 h2max(h2 a, h2 b) {
#if __has_builtin(__builtin_elementwise_max)
    return __builtin_elementwise_max(a, b);
#else
    h2 r;
    r.x = a.x > b.x ? a.x : b.x;
    r.y = a.y > b.y ? a.y : b.y;
    return r;
#endif
}

#define ENC_BLKS 256
#define TR_BLKS  1563            // ceil(100000/64), fused into K1 (leaf work)
#define S_BLKS   1024
#define S_PCH    98              // ceil(100000/1024)
#define NCOPY    8               // S replication factor (atomic-contention fix)
#define NPAIRS   (N_PTS / 2)     // 50000
#define M_BLKS   2048
#define M_CH     ((NPAIRS + M_BLKS - 1) / M_BLKS)   // 25

// ws layout (memset zeroes [0,32896): enc + S8):
//   [0,128)         enc (32 f, atomicAdd target)
//   [128,32896)     S8 (8 x 1024 f, replicated atomicAdd target)
//   [32896,34944)   invFG (512 f)
//   [34944,35968)   invHLG (256 h2)
//   [532480,...)    decT (N*32 fp16, 6.4 MB)
// Round-9 post-mortem: WRITE_SIZE 8.2MB == 2M atomics onto 1024 addresses
// (2048-deep RMW chains ~ 40us). Fix: 8 replicated copies, block b adds to
// copy b&7 -> 128-deep chains; k_main prologue reduces the 32KB in LDS.
// NO cross-block fences (round-7: writeback storm on non-coherent L2s).

// ---------------------------------------------------------------------------
// K1: encode (256 blocks) || dec transpose (1563 blocks) — independent leaves.
// ---------------------------------------------------------------------------
__global__ __launch_bounds__(256) void k_prep_tr(const float* __restrict__ x,
                                                 const float* __restrict__ encW,
                                                 const float* __restrict__ encB,
                                                 float* __restrict__ enc,
                                                 const float* __restrict__ dec,
                                                 __half* __restrict__ decT) {
    int b = blockIdx.x;
    if (b < ENC_BLKS) {
        int row = b & 31;
        int chunk = b >> 5;              // 0..7
        const int CH = N_PTS / 8;        // 12500
        int base = chunk * CH;
        const float4* W4 = reinterpret_cast<const float4*>(encW + (size_t)row * N_PTS + base);
        const float4* x4 = reinterpret_cast<const float4*>(x + base);
        const int nv = CH / 4;           // 3125
        float acc = 0.f;
        for (int idx = threadIdx.x; idx < nv; idx += 256) {
            float4 w = W4[idx];
            float4 xv = x4[idx];
            acc += w.x * xv.x + w.y * xv.y + w.z * xv.z + w.w * xv.w;
        }
        #pragma unroll
        for (int off = 32; off > 0; off >>= 1) acc += __shfl_down(acc, off);
        __shared__ float sred[4];
        int wid = threadIdx.x >> 6;
        if ((threadIdx.x & 63) == 0) sred[wid] = acc;
        __syncthreads();
        if (threadIdx.x == 0) {
            float s = sred[0] + sred[1] + sred[2] + sred[3];
            if (chunk == 0) s += encB[row];
            atomicAdd(enc + row, s);
        }
    } else {
        // ----- transpose dec [32,N] f32 -> decT [N,32] fp16 (64B rows)
        __shared__ float tile[32][65];
        int j0 = (b - ENC_BLKS) * 64;
        int col = threadIdx.x & 63;
        int r0 = threadIdx.x >> 6;       // 0..3
        #pragma unroll
        for (int it = 0; it < 8; ++it) {
            int row = it * 4 + r0;
            int j = j0 + col;
            float v = (j < N_PTS) ? dec[(size_t)row * N_PTS + j] : 0.f;
            tile[row][col] = v;
        }
        __syncthreads();
        #pragma unroll
        for (int it = 0; it < 4; ++it) {
            int idx = it * 256 + threadIdx.x;
            int j = idx >> 4;            // 0..63
            int p = idx & 15;            // i-pair
            int jj = j0 + j;
            if (jj < N_PTS) {
                __half2 h = __halves2half2(__float2half(tile[2 * p][j]),
                                           __float2half(tile[2 * p + 1][j]));
                *reinterpret_cast<__half2*>(decT + (size_t)jj * 32 + 2 * p) = h;
            }
        }
    }
}

// ---------------------------------------------------------------------------
// K_tab (1 block): build invFG[512] (f32) and invHLG[256] (packed h2) ONCE.
// invF[c*32+i] = 1/(sigmoid(enc.bw_w[i*16+c]+b)*MU/60)^2
// ---------------------------------------------------------------------------
__global__ __launch_bounds__(256) void k_tab(const float* __restrict__ enc_g,
                                             const float* __restrict__ bw_w,
                                             const float* __restrict__ bw_b,
                                             float* __restrict__ invFG,
                                             h2* __restrict__ invHLG) {
    __shared__ float encL[32];
    __shared__ float invF[512];
    if (threadIdx.x < 32) encL[threadIdx.x] = enc_g[threadIdx.x];
    __syncthreads();
    for (int r = threadIdx.x; r < 512; r += 256) {
        int i = r >> 4, c = r & 15;
        const float4* wr4 = reinterpret_cast<const float4*>(bw_w + (size_t)r * 32);
        float z = bw_b[r];
        #pragma unroll
        for (int p4 = 0; p4 < 8; ++p4) {
            float4 wv = wr4[p4];
            z = fmaf(encL[4 * p4 + 0], wv.x, z);
            z = fmaf(encL[4 * p4 + 1], wv.y, z);
            z = fmaf(encL[4 * p4 + 2], wv.z, z);
            z = fmaf(encL[4 * p4 + 3], wv.w, z);
        }
        float s = 1.f / (1.f + __expf(-z));
        float wmu = s * (MU_F / 60.0f);
        float iv = 1.f / (wmu * wmu);
        invF[c * 32 + i] = iv;
        invFG[c * 32 + i] = iv;
    }
    __syncthreads();
    {
        int t = threadIdx.x;             // 16c x 4q x 4tt
        int c = t >> 4, q = (t >> 2) & 3, tt = t & 3;
        int i0 = q * 8 + 2 * tt;
        invHLG[t] = h2pack(fminf(invF[c * 32 + i0], 6.0e4f),
                           fminf(invF[c * 32 + i0 + 1], 6.0e4f));
    }
}

// ---------------------------------------------------------------------------
// K2: S pass. 1024 blocks x 98 points, cell-ownership (thread owns 4 cells).
// Epilogue: atomicAdd into replica blockIdx&7 -> 128-deep chains (was 2048).
// ---------------------------------------------------------------------------
__global__ __launch_bounds__(256, 8) void k_S(const float* __restrict__ invFG,
                                              const float* __restrict__ nd,
                                              const int* __restrict__ labels,
                                              float* __restrict__ S8) {
    __shared__ float invF[512];
    if (threadIdx.x < 128)               // 2KB coalesced table load
        reinterpret_cast<float4*>(invF)[threadIdx.x] =
            reinterpret_cast<const float4*>(invFG)[threadIdx.x];
    __syncthreads();

    int kk = threadIdx.x & 31;
    int ig = threadIdx.x >> 5;           // 0..7
    int start = blockIdx.x * S_PCH;
    int jend = min(start + S_PCH, N_PTS);

    float a0 = 0.f, a1 = 0.f, a2 = 0.f, a3 = 0.f;

    // padded points get d=1e15 -> relu(1 - 1e30*inv) == 0 exactly (inv>=0.36).
    auto ld4 = [&](int jbase, float* d, int* cc) {
        #pragma unroll
        for (int u = 0; u < 4; ++u) {
            int j = jbase + u;
            int jc = min(j, N_PTS - 1);
            float dv = __builtin_nontemporal_load(&nd[(size_t)jc * 32 + kk]);
            cc[u] = labels[jc];          // uniform j -> scalar load
            d[u] = (j < jend) ? dv : 1.0e15f;
        }
    };
    float dA[4], dB[4], dC[4]; int cA[4], cB[4], cC[4];
    ld4(start, dA, cA);
    ld4(start + 4, dB, cB);
    for (int jj = start; jj < jend; jj += 4) {
        ld4(jj + 8, dC, cC);             // 3-deep: A compute, B ready, C inflight
        #pragma unroll
        for (int u = 0; u < 4; ++u) {
            float4 iv = *reinterpret_cast<const float4*>(&invF[cA[u] * 32 + ig * 4]);
            float d2 = dA[u] * dA[u];
            a0 += fmaxf(fmaf(d2, -iv.x, 1.f), 0.f);
            a1 += fmaxf(fmaf(d2, -iv.y, 1.f), 0.f);
            a2 += fmaxf(fmaf(d2, -iv.z, 1.f), 0.f);
            a3 += fmaxf(fmaf(d2, -iv.w, 1.f), 0.f);
        }
        #pragma unroll
        for (int u = 0; u < 4; ++u) {
            dA[u] = dB[u]; cA[u] = cB[u];
            dB[u] = dC[u]; cB[u] = cC[u];
        }
    }

    float* Sc = S8 + (size_t)(blockIdx.x & (NCOPY - 1)) * 1024;
    int cell = (ig * 4) * 32 + kk;       // i = ig*4+r -> cell + r*32
    atomicAdd(&Sc[cell], a0);            // device-scope, fence-free
    atomicAdd(&Sc[cell + 32], a1);
    atomicAdd(&Sc[cell + 64], a2);
    atomicAdd(&Sc[cell + 96], a3);
}

// ---------------------------------------------------------------------------
// K4 (main): decT gather loop, (256,6) (measured-best: 48us/44% occ; (256,8)
// was slightly worse — more blocks thrash L2 for the gather). Prologue
// reduces S8 (8x1024, 32KB, L2-resident) into LDS Sred and builds Eh from it.
// ---------------------------------------------------------------------------
__global__ __launch_bounds__(256, 6) void k_main(const h2* __restrict__ invHLG,
                                                 const float* __restrict__ enc_g,
                                                 const float* __restrict__ S8,
                                                 const float* __restrict__ nd,
                                                 const int* __restrict__ nid,
                                                 const int* __restrict__ labels,
                                                 const __half* __restrict__ decT,
                                                 float* __restrict__ out) {
    __shared__ h2 invHL[256];            // [c][q][t] : c*16 + q*4 + t
    __shared__ float Sred[1024];
    if (threadIdx.x < 64)                // 1KB coalesced copy
        reinterpret_cast<uint4*>(invHL)[threadIdx.x] =
            reinterpret_cast<const uint4*>(invHLG)[threadIdx.x];
    for (int t = threadIdx.x; t < 1024; t += 256) {
        float s = 0.f;
        #pragma unroll
        for (int c = 0; c < NCOPY; ++c)
            s += S8[(size_t)c * 1024 + t];
        Sred[t] = s;
    }
    __syncthreads();

    int lane = threadIdx.x & 63;
    int R = lane >> 2;                   // 0..15
    int q = lane & 3;                    // i-quarter / row quad

    // per-thread E tables: ELf[t] = enc[t>>5]/S[t]*E_SCALE; (i0*32+R)>>5 == i0.
    h2 EhA[4], EhB[4];
    #pragma unroll
    for (int t = 0; t < 4; ++t) {
        int i0 = q * 8 + 2 * t;
        float e0 = enc_g[i0], e1 = enc_g[i0 + 1];
        float sA0 = Sred[i0 * 32 + R],      sA1 = Sred[(i0 + 1) * 32 + R];
        float sB0 = Sred[i0 * 32 + R + 16], sB1 = Sred[(i0 + 1) * 32 + R + 16];
        EhA[t] = h2pack(e0 / sA0 * E_SCALE, e1 / sA1 * E_SCALE);
        EhB[t] = h2pack(e0 / sB0 * E_SCALE, e1 / sB1 * E_SCALE);
    }
    const h2 zero2 = h2pack(0.f, 0.f);
    const h2 one2 = h2pack(1.f, 1.f);

    int w = threadIdx.x >> 6;            // wave 0..3
    int start = blockIdx.x * M_CH;
    int pend = min(start + M_CH, NPAIRS);
    int pa = start + w;
    const uint4* decQ = reinterpret_cast<const uint4*>(decT);
    if (pa >= pend) return;

    auto load_ldd = [&](int pc, int* id, float* dd, int& c0, int& c1) {
        pc = min(pc, NPAIRS - 1);
        int j0 = 2 * pc, j1 = j0 + 1;
        #pragma unroll
        for (int s = 0; s < 4; ++s) {
            size_t idx = (size_t)((s >> 1) ? j1 : j0) * 32 + (s & 1) * 16 + R;
            id[s] = __builtin_nontemporal_load(&nid[idx]);
            dd[s] = __builtin_nontemporal_load(&nd[idx]);
        }
        c0 = labels[j0];
        c1 = labels[j1];
    };
    auto load_rows = [&](const int* id, uint4* r) {
        #pragma unroll
        for (int s = 0; s < 4; ++s)
            r[s] = decQ[(size_t)id[s] * 4 + q];
    };
    auto load_ih = [&](int c0, int c1, h2* ih0, h2* ih1) {
        uint4 a = *reinterpret_cast<const uint4*>(&invHL[c0 * 16 + q * 4]);
        uint4 bq = *reinterpret_cast<const uint4*>(&invHL[c1 * 16 + q * 4]);
        ih0[0] = __builtin_bit_cast(h2, a.x);  ih0[1] = __builtin_bit_cast(h2, a.y);
        ih0[2] = __builtin_bit_cast(h2, a.z);  ih0[3] = __builtin_bit_cast(h2, a.w);
        ih1[0] = __builtin_bit_cast(h2, bq.x); ih1[1] = __builtin_bit_cast(h2, bq.y);
        ih1[2] = __builtin_bit_cast(h2, bq.z); ih1[3] = __builtin_bit_cast(h2, bq.w);
    };

    int ida[4], idb[4]; float dda[4], ddb[4];
    int ca0, ca1, cb0, cb1;
    uint4 ra[4], rb[4];
    h2 ihA0[4], ihA1[4];

    load_ldd(pa, ida, dda, ca0, ca1);
    load_ldd(pa + 4, idb, ddb, cb0, cb1);
    load_rows(ida, ra);
    load_ih(ca0, ca1, ihA0, ihA1);

    while (pa < pend) {
        load_rows(idb, rb);
        h2 ihB0[4], ihB1[4];
        load_ih(cb0, cb1, ihB0, ihB1);
        int idc[4]; float ddc[4]; int cc0, cc1;
        load_ldd(pa + 8, idc, ddc, cc0, cc1);

        float d20 = dda[0] * dda[0];
        float d21 = dda[1] * dda[1];
        float d22 = dda[2] * dda[2];
        float d23 = dda[3] * dda[3];
        h2 md0 = h2pack(-d20, -d20);
        h2 md1 = h2pack(-d21, -d21);
        h2 md2 = h2pack(-d22, -d22);
        h2 md3 = h2pack(-d23, -d23);

        float a0 = 0.f, a1 = 0.f, a2 = 0.f, a3 = 0.f;
        #pragma unroll
        for (int t = 0; t < 4; ++t) {
            uint dw0 = (t == 0) ? ra[0].x : (t == 1) ? ra[0].y : (t == 2) ? ra[0].z : ra[0].w;
            uint dw1 = (t == 0) ? ra[1].x : (t == 1) ? ra[1].y : (t == 2) ? ra[1].z : ra[1].w;
            uint dw2 = (t == 0) ? ra[2].x : (t == 1) ? ra[2].y : (t == 2) ? ra[2].z : ra[2].w;
            uint dw3 = (t == 0) ? ra[3].x : (t == 1) ? ra[3].y : (t == 2) ? ra[3].z : ra[3].w;
            {
                h2 wv = h2max(h2fma(md0, ihA0[t], one2), zero2);
                a0 = fdot2f(wv * EhA[t], __builtin_bit_cast(h2, dw0), a0);
            }
            {
                h2 wv = h2max(h2fma(md1, ihA0[t], one2), zero2);
                a1 = fdot2f(wv * EhB[t], __builtin_bit_cast(h2, dw1), a1);
            }
            {
                h2 wv = h2max(h2fma(md2, ihA1[t], one2), zero2);
                a2 = fdot2f(wv * EhA[t], __builtin_bit_cast(h2, dw2), a2);
            }
            {
                h2 wv = h2max(h2fma(md3, ihA1[t], one2), zero2);
                a3 = fdot2f(wv * EhB[t], __builtin_bit_cast(h2, dw3), a3);
            }
        }
        float u = a0 + a1;               // j0 partial
        float v = a2 + a3;               // j1 partial
        #pragma unroll
        for (int off = 32; off > 0; off >>= 1) {
            u += __shfl_xor(u, off);
            v += __shfl_xor(v, off);
        }
        if (lane == 0)  out[2 * pa]     = u * E_SCALE_INV;
        if (lane == 32) out[2 * pa + 1] = v * E_SCALE_INV;

        ca0 = cb0; ca1 = cb1; cb0 = cc0; cb1 = cc1;
        #pragma unroll
        for (int s = 0; s < 4; ++s) {
            dda[s] = ddb[s]; ddb[s] = ddc[s];
            ida[s] = idb[s]; idb[s] = idc[s];
            ra[s] = rb[s];
            ihA0[s] = ihB0[s]; ihA1[s] = ihB1[s];
        }
        pa += 4;
    }
}

// ---------------------------------------------------------------------------
extern "C" void kernel_launch(void* const* d_in, const int* in_sizes, int n_in,
                              void* d_out, int out_size, void* d_ws, size_t ws_size,
                              hipStream_t stream) {
    const float* x     = (const float*)d_in[0];
    const float* enc_w = (const float*)d_in[1];
    const float* enc_b = (const float*)d_in[2];
    const float* dec   = (const float*)d_in[3];
    const float* bw_w  = (const float*)d_in[4];
    const float* bw_b  = (const float*)d_in[5];
    const float* nd    = (const float*)d_in[6];
    const int*   nid   = (const int*)d_in[7];
    const int*   labels= (const int*)d_in[8];
    float* out = (float*)d_out;

    char* ws = (char*)d_ws;
    float* enc    = (float*)(ws + 0);
    float* S8     = (float*)(ws + 128);
    float* invFG  = (float*)(ws + 32896);
    h2*    invHLG = (h2*)(ws + 34944);
    __half* decT  = (__half*)(ws + 532480);

    (void)hipMemsetAsync(d_ws, 0, 32896, stream);    // enc + S8
    k_prep_tr<<<dim3(ENC_BLKS + TR_BLKS), dim3(256), 0, stream>>>(
        x, enc_w, enc_b, enc, dec, decT);
    k_tab<<<dim3(1), dim3(256), 0, stream>>>(enc, bw_w, bw_b, invFG, invHLG);
    k_S<<<dim3(S_BLKS), dim3(256), 0, stream>>>(invFG, nd, labels, S8);
    k_main<<<dim3(M_BLKS), dim3(256), 0, stream>>>(invHLG, enc, S8, nd, nid,
                                                   labels, decT, out);
}